// Round 12
// baseline (165.750 us; speedup 1.0000x reference)
//
#include <hip/hip_runtime.h>
#include <hip/hip_bf16.h>

// Problem constants
#define BATCH 4
#define TSEQ  2048
#define CDIM  768
#define HNUM  12
#define DHEAD 64
#define NQKV  (3*CDIM)          // 2304
#define BTOT  (BATCH*TSEQ)      // 8192
#define BH    (BATCH*HNUM)      // 48

typedef unsigned short u16;
typedef __attribute__((ext_vector_type(8))) __bf16 bf16x8;
typedef __attribute__((ext_vector_type(4))) float f32x4;

#define MFMA16(a,b,c) __builtin_amdgcn_mfma_f32_16x16x32_bf16((a),(b),(c),0,0,0)

// fp32 -> bf16 RNE (hand-rolled, version-independent)
__device__ __forceinline__ u16 f2b(float f) {
    union { float f; unsigned u; } v; v.f = f;
    unsigned u = v.u;
    unsigned r = (u + 0x7fffu + ((u >> 16) & 1u)) >> 16;
    return (u16)r;
}

// pack 2 fp32 -> 2 bf16 in one u32 (lo -> bits 15:0), RNE
__device__ __forceinline__ unsigned cvtpk(float lo, float hi) {
    unsigned r;
    asm("v_cvt_pk_bf16_f32 %0, %1, %2" : "=v"(r) : "v"(lo), "v"(hi));
    return r;
}

// raw 2^x
__device__ __forceinline__ float fexp2(float x) {
    float r;
    asm("v_exp_f32 %0, %1" : "=v"(r) : "v"(x));
    return r;
}

__device__ __forceinline__ void gload_lds(const void* g, void* l) {
    __builtin_amdgcn_global_load_lds(
        (const __attribute__((address_space(1))) void*)g,
        (__attribute__((address_space(3))) void*)l, 16, 0, 0);
}

// ---------------- fused prep: x-cast + both weight transposes, ONE launch ----
// blocks [0, 6144)            : cast x fp32 -> bf16 (float4/ushort4)
// blocks [6144, 6144+2304)    : 32x32 transpose tiles of W_attn / W_proj
#define CAST_BLKS (BTOT * CDIM / 4 / 256)          // 6144
#define TA_BLKS   ((NQKV / 32) * (CDIM / 32))      // 72*24 = 1728
#define TP_BLKS   ((CDIM / 32) * (CDIM / 32))      // 24*24 = 576
__global__ __launch_bounds__(256) void prep(
        const float* __restrict__ x, u16* __restrict__ xb,
        const float* __restrict__ Wa, const float* __restrict__ Wp,
        u16* __restrict__ WaT, u16* __restrict__ WpT) {
    __shared__ float tile[32][33];
    const int bx = blockIdx.x, tid = threadIdx.x;
    if (bx < CAST_BLKS) {
        int i = bx * 256 + tid;
        float4 a = reinterpret_cast<const float4*>(x)[i];
        ushort4 o;
        o.x = f2b(a.x); o.y = f2b(a.y); o.z = f2b(a.z); o.w = f2b(a.w);
        reinterpret_cast<ushort4*>(xb)[i] = o;
        return;
    }
    int bz = bx - CAST_BLKS;
    const float* in; u16* out; int Cc;
    int nxa = NQKV / 32;
    int cx, ry;
    if (bz < TA_BLKS) { in = Wa; out = WaT; Cc = NQKV; cx = bz % nxa; ry = bz / nxa; }
    else { bz -= TA_BLKS; in = Wp; out = WpT; Cc = CDIM; cx = bz % (CDIM/32); ry = bz / (CDIM/32); }
    int c0 = cx * 32, r0 = ry * 32;
    int tx = tid & 31, ty = tid >> 5;             // (32,8)
    #pragma unroll
    for (int i = 0; i < 32; i += 8)
        tile[ty + i][tx] = in[(size_t)(r0 + ty + i) * Cc + c0 + tx];
    __syncthreads();
    #pragma unroll
    for (int i = 0; i < 32; i += 8)
        out[(size_t)(c0 + ty + i) * CDIM + r0 + tx] = f2b(tile[tx][ty + i]);
}

// ---------------- GEMM: C[M x N] = A[M x K] * Bt[N x K]^T (+bias) ------------
// R11 best: 2-buf, stage(kt+1)->compute(kt)->syncthreads, 4-slot XOR swizzle
// both tiles both sides (conflicts measured 0), swapped-operand MFMA (C^T),
// packed epilogue, XCD-aware grid swizzle.
template<int MODE, int NX>
__global__ __launch_bounds__(256) void gemm_bt(
        const u16* __restrict__ A, const u16* __restrict__ Bt,
        const float* __restrict__ bias,
        u16* __restrict__ qb, u16* __restrict__ kb, u16* __restrict__ vtb,
        float* __restrict__ outf, int K) {
    __shared__ u16 sA[2][128 * 32];
    __shared__ u16 sB[2][128 * 32];
    const int tid = threadIdx.x;
    const int lane = tid & 63;
    const int w = tid >> 6;
    const int wr = w >> 1, wc = w & 1;          // 64x64 quadrant per wave
    const int g = lane >> 4, lq = lane & 15;
    const int cpx = gridDim.x >> 3;
    const int wg = ((int)blockIdx.x & 7) * cpx + ((int)blockIdx.x >> 3);
    const int bx = wg % NX, by = wg / NX;
    const int m0 = by * 128, n0 = bx * 128;

    f32x4 acc[4][4] = {};

    auto stage = [&](int buf, int kt) {
        #pragma unroll
        for (int i = 0; i < 2; ++i) {
            int c = i * 256 + tid;              // 512 chunks of 16B
            int r = c >> 2, s = c & 3;
            int l = s ^ ((r >> 1) & 3);
            gload_lds(A  + (size_t)(m0 + r) * K + kt * 32 + l * 8, &sA[buf][c * 8]);
            gload_lds(Bt + (size_t)(n0 + r) * K + kt * 32 + l * 8, &sB[buf][c * 8]);
        }
    };

    const int KT = K / 32;                      // 24
    stage(0, 0);
    __syncthreads();
    for (int kt = 0; kt < KT; ++kt) {
        if (kt + 1 < KT) stage((kt + 1) & 1, kt + 1);   // overlaps compute(kt)
        const u16* cA = sA[kt & 1];
        const u16* cB = sB[kt & 1];
        bf16x8 af[4], bfr[4];
        #pragma unroll
        for (int m = 0; m < 4; ++m) {
            int r = wr * 64 + m * 16 + lq;
            af[m] = *(const bf16x8*)&cA[r * 32 + ((g ^ ((r >> 1) & 3)) << 3)];
        }
        #pragma unroll
        for (int n = 0; n < 4; ++n) {
            int r = wc * 64 + n * 16 + lq;
            bfr[n] = *(const bf16x8*)&cB[r * 32 + ((g ^ ((r >> 1) & 3)) << 3)];
        }
        __builtin_amdgcn_s_setprio(1);
        #pragma unroll
        for (int m = 0; m < 4; ++m)
            #pragma unroll
            for (int n = 0; n < 4; ++n)
                acc[m][n] = MFMA16(bfr[n], af[m], acc[m][n]);   // C^T tile
        __builtin_amdgcn_s_setprio(0);
        __syncthreads();
    }

    if (MODE == 0) {
        const int which = n0 / CDIM;            // 0=q 1=k 2=v, uniform per block
        #pragma unroll
        for (int m = 0; m < 4; ++m) {
            const int rg = m0 + wr * 64 + m * 16 + lq;
            const int b = rg >> 11, t = rg & (TSEQ - 1);
            #pragma unroll
            for (int n = 0; n < 4; ++n) {
                const int cg = n0 + wc * 64 + n * 16 + (g << 2);
                const int c  = cg - which * CDIM;
                const int h  = c >> 6, d = c & 63;
                const size_t bh = (size_t)(b * HNUM + h);
                const float4 bv = *(const float4*)&bias[cg];
                const float v0 = acc[m][n][0] + bv.x;
                const float v1 = acc[m][n][1] + bv.y;
                const float v2 = acc[m][n][2] + bv.z;
                const float v3 = acc[m][n][3] + bv.w;
                if (which == 0) {
                    const float s = 0.1803368801111243f;   // 0.125 * log2(e)
                    ushort4 pv;
                    pv.x = f2b(v0 * s); pv.y = f2b(v1 * s);
                    pv.z = f2b(v2 * s); pv.w = f2b(v3 * s);
                    *(ushort4*)&qb[(bh * TSEQ + t) * DHEAD + d] = pv;
                } else if (which == 1) {
                    ushort4 pv;
                    pv.x = f2b(v0); pv.y = f2b(v1); pv.z = f2b(v2); pv.w = f2b(v3);
                    *(ushort4*)&kb[(bh * TSEQ + t) * DHEAD + d] = pv;
                } else {
                    vtb[(bh * DHEAD + d + 0) * TSEQ + t] = f2b(v0);
                    vtb[(bh * DHEAD + d + 1) * TSEQ + t] = f2b(v1);
                    vtb[(bh * DHEAD + d + 2) * TSEQ + t] = f2b(v2);
                    vtb[(bh * DHEAD + d + 3) * TSEQ + t] = f2b(v3);
                }
            }
        }
    } else {
        #pragma unroll
        for (int m = 0; m < 4; ++m) {
            const int rg = m0 + wr * 64 + m * 16 + lq;
            #pragma unroll
            for (int n = 0; n < 4; ++n) {
                const int cg = n0 + wc * 64 + n * 16 + (g << 2);
                const float4 bv = *(const float4*)&bias[cg];
                float4 ov;
                ov.x = acc[m][n][0] + bv.x;
                ov.y = acc[m][n][1] + bv.y;
                ov.z = acc[m][n][2] + bv.z;
                ov.w = acc[m][n][3] + bv.w;
                *(float4*)&outf[(size_t)rg * CDIM + cg] = ov;
            }
        }
    }
}

// ---------------- causal flash attention: 32 q-rows per wave -----------------
// 768 blocks (16 q-tiles of 128 x 48 bh), longest first. 256 threads = 4
// waves; wave owns 32 q rows (two 16-row halves sharing K/V LDS reads).
// KVBLK=64 double-buffered. Per iter: 16 QK^T + 16 PV + 4 ls MFMA — 2x the
// work of R8 per fixed stage+barrier overhead; block-iters halve (13056).
__global__ __launch_bounds__(256, 4) void attn_fwd(
        const u16* __restrict__ qb, const u16* __restrict__ kb,
        const u16* __restrict__ vtb, u16* __restrict__ yb) {
    __shared__ u16 sK[2][64 * 64];
    __shared__ u16 sVt[2][64 * 64];
    const int qt = 15 - (int)(blockIdx.x / BH);  // 128-row q-tile, longest first
    const int bh = blockIdx.x % BH;
    const int b = bh / HNUM, h = bh % HNUM;
    const int tid = threadIdx.x, lane = tid & 63, w = tid >> 6;   // w 0..3
    const int g = lane >> 4, lq = lane & 15;
    const int qlo = qt * 128 + w * 32;           // wave's 32 q rows
    const u16* qbase = qb  + (size_t)bh * TSEQ * DHEAD;
    const u16* kbase = kb  + (size_t)bh * TSEQ * DHEAD;
    const u16* vbase = vtb + (size_t)bh * DHEAD * TSEQ;

    // Q fragments: half m covers rows qlo+m*16 .. qlo+m*16+15
    bf16x8 qf[2][2];
    #pragma unroll
    for (int m = 0; m < 2; ++m)
        #pragma unroll
        for (int ks = 0; ks < 2; ++ks)
            qf[m][ks] = *(const bf16x8*)&qbase[(size_t)(qlo + m * 16 + lq) * DHEAD
                                               + ks * 32 + g * 8];

    union { unsigned u[4]; bf16x8 v; } ones;
    #pragma unroll
    for (int i = 0; i < 4; ++i) ones.u[i] = 0x3f803f80u;

    f32x4 o[2][4] = {};
    f32x4 ls[2] = {};                            // row sums, O-layout per half
    float mx[2] = { -__builtin_inff(), -__builtin_inff() };

    auto STAGE = [&](int buf, int kt) {
        const int k0 = kt << 6;
        #pragma unroll
        for (int i = 0; i < 2; ++i) {
            int chunk = i * 256 + tid;           // 512 chunks of 16B per tile
            int srow = chunk >> 3;
            int cb = ((chunk & 7) << 4) ^ ((srow & 7) << 4);   // logical byte col
            gload_lds(kbase + (size_t)(k0 + srow) * DHEAD + (cb >> 1), &sK[buf][chunk * 8]);
            gload_lds(vbase + (size_t)srow * TSEQ + k0 + (cb >> 1),    &sVt[buf][chunk * 8]);
        }
    };

    const int nk = 2 * qt + 2;
    STAGE(0, 0);
    __syncthreads();
    for (int kt = 0; kt < nk; ++kt) {
        const int k0 = kt << 6;
        if (kt + 1 < nk) STAGE((kt + 1) & 1, kt + 1);   // prefetch overlaps compute
        if (k0 <= qlo + 31) {                    // wave-uniform activity
            const u16* cK = sK[kt & 1];
            const u16* cV = sVt[kt & 1];
            // S^T both halves; kf shared between halves
            f32x4 s[2][4];
            #pragma unroll
            for (int m = 0; m < 2; ++m)
                #pragma unroll
                for (int n = 0; n < 4; ++n) s[m][n] = f32x4{0.f, 0.f, 0.f, 0.f};
            __builtin_amdgcn_s_setprio(1);
            #pragma unroll
            for (int n = 0; n < 4; ++n) {
                #pragma unroll
                for (int ks = 0; ks < 2; ++ks) {
                    int r = n * 16 + lq;
                    int lb = (r * 128 + (ks * 32 + g * 8) * 2) ^ ((r & 7) << 4);
                    bf16x8 kf = *(const bf16x8*)((const char*)cK + lb);
                    s[0][n] = MFMA16(kf, qf[0][ks], s[0][n]);
                    s[1][n] = MFMA16(kf, qf[1][ks], s[1][n]);
                }
            }
            __builtin_amdgcn_s_setprio(0);
            // causal mask (near-diagonal tiles only)
            if (k0 + 63 > qlo) {
                #pragma unroll
                for (int m = 0; m < 2; ++m) {
                    const int qa = qlo + m * 16 + lq;
                    #pragma unroll
                    for (int n = 0; n < 4; ++n)
                        #pragma unroll
                        for (int j = 0; j < 4; ++j)
                            if (k0 + n * 16 + g * 4 + j > qa) s[m][n][j] = -__builtin_inff();
                }
            }
            // row max per half
            float tmax[2];
            #pragma unroll
            for (int m = 0; m < 2; ++m) {
                float t0 = fmaxf(fmaxf(s[m][0][0], s[m][0][1]), fmaxf(s[m][0][2], s[m][0][3]));
                float t1 = fmaxf(fmaxf(s[m][1][0], s[m][1][1]), fmaxf(s[m][1][2], s[m][1][3]));
                float t2 = fmaxf(fmaxf(s[m][2][0], s[m][2][1]), fmaxf(s[m][2][2], s[m][2][3]));
                float t3 = fmaxf(fmaxf(s[m][3][0], s[m][3][1]), fmaxf(s[m][3][2], s[m][3][3]));
                float tm = fmaxf(fmaxf(t0, t1), fmaxf(t2, t3));
                tm = fmaxf(tm, __shfl_xor(tm, 16));
                tm = fmaxf(tm, __shfl_xor(tm, 32));
                tmax[m] = tm;
            }
            // defer-max (THR=8 exp2 units), combined trigger, per-half rescale
            if (__any(tmax[0] > mx[0] + 8.0f || tmax[1] > mx[1] + 8.0f)) {
                #pragma unroll
                for (int m = 0; m < 2; ++m) {
                    float mnew = fmaxf(mx[m], tmax[m]);
                    float sc = fexp2(mx[m] - mnew);
                    mx[m] = mnew;
                    #pragma unroll
                    for (int j = 0; j < 4; ++j) {
                        float scj = __shfl(sc, (lane & 48) | ((g << 2) + j));
                        ls[m][j] *= scj;
                        #pragma unroll
                        for (int n = 0; n < 4; ++n) o[m][n][j] *= scj;
                    }
                }
            }
            unsigned apk[2][4], bpk[2][4];
            #pragma unroll
            for (int m = 0; m < 2; ++m)
                #pragma unroll
                for (int n = 0; n < 4; ++n) {
                    float p0 = fexp2(s[m][n][0] - mx[m]);
                    float p1 = fexp2(s[m][n][1] - mx[m]);
                    float p2 = fexp2(s[m][n][2] - mx[m]);
                    float p3 = fexp2(s[m][n][3] - mx[m]);
                    apk[m][n] = cvtpk(p0, p1);
                    bpk[m][n] = cvtpk(p2, p3);
                }
            // PV both halves; vf shared between halves
            const int s0l = lq + ((lane & 16) << 1);
            const bool hi = (lane & 32) != 0;
            #pragma unroll
            for (int ks = 0; ks < 2; ++ks) {
                union { unsigned u[4]; bf16x8 v; } pa[2];
                #pragma unroll
                for (int m = 0; m < 2; ++m) {
                    unsigned A0  = (unsigned)__shfl((int)apk[m][2 * ks],     s0l);
                    unsigned B0  = (unsigned)__shfl((int)bpk[m][2 * ks],     s0l);
                    unsigned A1  = (unsigned)__shfl((int)apk[m][2 * ks + 1], s0l);
                    unsigned B1  = (unsigned)__shfl((int)bpk[m][2 * ks + 1], s0l);
                    unsigned A0h = (unsigned)__shfl((int)apk[m][2 * ks],     s0l + 16);
                    unsigned B0h = (unsigned)__shfl((int)bpk[m][2 * ks],     s0l + 16);
                    unsigned A1h = (unsigned)__shfl((int)apk[m][2 * ks + 1], s0l + 16);
                    unsigned B1h = (unsigned)__shfl((int)bpk[m][2 * ks + 1], s0l + 16);
                    pa[m].u[0] = hi ? A1  : A0;
                    pa[m].u[1] = hi ? B1  : B0;
                    pa[m].u[2] = hi ? A1h : A0h;
                    pa[m].u[3] = hi ? B1h : B0h;
                }
                __builtin_amdgcn_s_setprio(1);
                #pragma unroll
                for (int n = 0; n < 4; ++n) {
                    int d = n * 16 + lq;
                    int lb = (d * 128 + (ks * 32 + g * 8) * 2) ^ ((d & 7) << 4);
                    bf16x8 vf = *(const bf16x8*)((const char*)cV + lb);
                    o[0][n] = MFMA16(pa[0].v, vf, o[0][n]);
                    o[1][n] = MFMA16(pa[1].v, vf, o[1][n]);
                }
                ls[0] = MFMA16(pa[0].v, ones.v, ls[0]);
                ls[1] = MFMA16(pa[1].v, ones.v, ls[1]);
                __builtin_amdgcn_s_setprio(0);
            }
        }
        __syncthreads();
    }

    // epilogue: y[b, t, h*64 + d] bf16 ; O rows q = g*4+j per half
    #pragma unroll
    for (int m = 0; m < 2; ++m)
        #pragma unroll
        for (int j = 0; j < 4; ++j) {
            float inv = 1.f / ls[m][j];
            const int t = qlo + m * 16 + g * 4 + j;
            #pragma unroll
            for (int n = 0; n < 4; ++n) {
                const int c = h * DHEAD + n * 16 + lq;
                yb[((size_t)b * TSEQ + t) * CDIM + c] = f2b(o[m][n][j] * inv);
            }
        }
}

extern "C" void kernel_launch(void* const* d_in, const int* in_sizes, int n_in,
                              void* d_out, int out_size, void* d_ws, size_t ws_size,
                              hipStream_t stream) {
    const float* x      = (const float*)d_in[0];
    const float* W_attn = (const float*)d_in[1];
    const float* b_attn = (const float*)d_in[2];
    const float* W_proj = (const float*)d_in[3];
    const float* b_proj = (const float*)d_in[4];
    float* out = (float*)d_out;

    // workspace layout (bf16 = u16). yb aliases xb (xb dead after GEMM1).
    u16* ws = (u16*)d_ws;
    u16* xb     = ws;                                   // [BTOT][CDIM]
    u16* yb     = xb;                                   // [BTOT][CDIM] (alias)
    u16* WattnT = xb     + (size_t)BTOT * CDIM;         // [NQKV][CDIM]
    u16* WprojT = WattnT + (size_t)NQKV * CDIM;         // [CDIM][CDIM]
    u16* qb     = WprojT + (size_t)CDIM * CDIM;         // [BH][TSEQ][DHEAD]
    u16* kb     = qb     + (size_t)BH * TSEQ * DHEAD;
    u16* vtb    = kb     + (size_t)BH * TSEQ * DHEAD;   // [BH][DHEAD][TSEQ]

    // 1) fused prep: x cast + both weight transposes (one launch)
    prep<<<dim3(CAST_BLKS + TA_BLKS + TP_BLKS), 256, 0, stream>>>(
        x, xb, W_attn, W_proj, WattnT, WprojT);

    // 2) QKV projection + scatter (1152 blocks, XCD-swizzled, conflict-free LDS)
    gemm_bt<0, NQKV / 128><<<dim3((NQKV / 128) * (BTOT / 128)), 256, 0, stream>>>(
        xb, WattnT, b_attn, qb, kb, vtb, nullptr, CDIM);

    // 3) causal flash attention (768 blocks, 32 q-rows/wave, longest first)
    attn_fwd<<<dim3((TSEQ / 128) * BH), 256, 0, stream>>>(qb, kb, vtb, yb);

    // 4) output projection (384 blocks, XCD-swizzled, conflict-free LDS)
    gemm_bt<1, CDIM / 128><<<dim3((CDIM / 128) * (BTOT / 128)), 256, 0, stream>>>(
        yb, WprojT, b_proj, nullptr, nullptr, nullptr, out, CDIM);
}

// Round 13
// 139.790 us; speedup vs baseline: 1.1857x; 1.1857x over previous
//
#include <hip/hip_runtime.h>
#include <hip/hip_bf16.h>

// Problem constants
#define BATCH 4
#define TSEQ  2048
#define CDIM  768
#define HNUM  12
#define DHEAD 64
#define NQKV  (3*CDIM)          // 2304
#define BTOT  (BATCH*TSEQ)      // 8192
#define BH    (BATCH*HNUM)      // 48

typedef unsigned short u16;
typedef __attribute__((ext_vector_type(8))) __bf16 bf16x8;
typedef __attribute__((ext_vector_type(4))) float f32x4;

#define MFMA16(a,b,c) __builtin_amdgcn_mfma_f32_16x16x32_bf16((a),(b),(c),0,0,0)

// fp32 -> bf16 RNE (hand-rolled, version-independent)
__device__ __forceinline__ u16 f2b(float f) {
    union { float f; unsigned u; } v; v.f = f;
    unsigned u = v.u;
    unsigned r = (u + 0x7fffu + ((u >> 16) & 1u)) >> 16;
    return (u16)r;
}

// pack 2 fp32 -> 2 bf16 in one u32 (lo -> bits 15:0), RNE
__device__ __forceinline__ unsigned cvtpk(float lo, float hi) {
    unsigned r;
    asm("v_cvt_pk_bf16_f32 %0, %1, %2" : "=v"(r) : "v"(lo), "v"(hi));
    return r;
}

// raw 2^x
__device__ __forceinline__ float fexp2(float x) {
    float r;
    asm("v_exp_f32 %0, %1" : "=v"(r) : "v"(x));
    return r;
}

__device__ __forceinline__ void gload_lds(const void* g, void* l) {
    __builtin_amdgcn_global_load_lds(
        (const __attribute__((address_space(1))) void*)g,
        (__attribute__((address_space(3))) void*)l, 16, 0, 0);
}

// ---------------- fused prep: x-cast + both weight transposes, ONE launch ----
#define CAST_BLKS (BTOT * CDIM / 4 / 256)          // 6144
#define TA_BLKS   ((NQKV / 32) * (CDIM / 32))      // 1728
#define TP_BLKS   ((CDIM / 32) * (CDIM / 32))      // 576
__global__ __launch_bounds__(256) void prep(
        const float* __restrict__ x, u16* __restrict__ xb,
        const float* __restrict__ Wa, const float* __restrict__ Wp,
        u16* __restrict__ WaT, u16* __restrict__ WpT) {
    __shared__ float tile[32][33];
    const int bx = blockIdx.x, tid = threadIdx.x;
    if (bx < CAST_BLKS) {
        int i = bx * 256 + tid;
        float4 a = reinterpret_cast<const float4*>(x)[i];
        ushort4 o;
        o.x = f2b(a.x); o.y = f2b(a.y); o.z = f2b(a.z); o.w = f2b(a.w);
        reinterpret_cast<ushort4*>(xb)[i] = o;
        return;
    }
    int bz = bx - CAST_BLKS;
    const float* in; u16* out; int Cc;
    int nxa = NQKV / 32;
    int cx, ry;
    if (bz < TA_BLKS) { in = Wa; out = WaT; Cc = NQKV; cx = bz % nxa; ry = bz / nxa; }
    else { bz -= TA_BLKS; in = Wp; out = WpT; Cc = CDIM; cx = bz % (CDIM/32); ry = bz / (CDIM/32); }
    int c0 = cx * 32, r0 = ry * 32;
    int tx = tid & 31, ty = tid >> 5;             // (32,8)
    #pragma unroll
    for (int i = 0; i < 32; i += 8)
        tile[ty + i][tx] = in[(size_t)(r0 + ty + i) * Cc + c0 + tx];
    __syncthreads();
    #pragma unroll
    for (int i = 0; i < 32; i += 8)
        out[(size_t)(c0 + ty + i) * CDIM + r0 + tx] = f2b(tile[tx][ty + i]);
}

// ---------------- GEMM1: QKV projection (R11 best, unchanged) ----------------
// 2-buf, stage(kt+1)->compute(kt)->syncthreads, 4-slot XOR swizzle both tiles
// both sides (conflicts measured 0), swapped-operand MFMA (C^T), packed
// epilogue, XCD-aware grid swizzle.
template<int NX>
__global__ __launch_bounds__(256) void gemm_qkv(
        const u16* __restrict__ A, const u16* __restrict__ Bt,
        const float* __restrict__ bias,
        u16* __restrict__ qb, u16* __restrict__ kb, u16* __restrict__ vtb,
        int K) {
    __shared__ u16 sA[2][128 * 32];
    __shared__ u16 sB[2][128 * 32];
    const int tid = threadIdx.x;
    const int lane = tid & 63;
    const int w = tid >> 6;
    const int wr = w >> 1, wc = w & 1;          // 64x64 quadrant per wave
    const int g = lane >> 4, lq = lane & 15;
    const int cpx = gridDim.x >> 3;
    const int wg = ((int)blockIdx.x & 7) * cpx + ((int)blockIdx.x >> 3);
    const int bx = wg % NX, by = wg / NX;
    const int m0 = by * 128, n0 = bx * 128;

    f32x4 acc[4][4] = {};

    auto stage = [&](int buf, int kt) {
        #pragma unroll
        for (int i = 0; i < 2; ++i) {
            int c = i * 256 + tid;              // 512 chunks of 16B
            int r = c >> 2, s = c & 3;
            int l = s ^ ((r >> 1) & 3);
            gload_lds(A  + (size_t)(m0 + r) * K + kt * 32 + l * 8, &sA[buf][c * 8]);
            gload_lds(Bt + (size_t)(n0 + r) * K + kt * 32 + l * 8, &sB[buf][c * 8]);
        }
    };

    const int KT = K / 32;                      // 24
    stage(0, 0);
    __syncthreads();
    for (int kt = 0; kt < KT; ++kt) {
        if (kt + 1 < KT) stage((kt + 1) & 1, kt + 1);   // overlaps compute(kt)
        const u16* cA = sA[kt & 1];
        const u16* cB = sB[kt & 1];
        bf16x8 af[4], bfr[4];
        #pragma unroll
        for (int m = 0; m < 4; ++m) {
            int r = wr * 64 + m * 16 + lq;
            af[m] = *(const bf16x8*)&cA[r * 32 + ((g ^ ((r >> 1) & 3)) << 3)];
        }
        #pragma unroll
        for (int n = 0; n < 4; ++n) {
            int r = wc * 64 + n * 16 + lq;
            bfr[n] = *(const bf16x8*)&cB[r * 32 + ((g ^ ((r >> 1) & 3)) << 3)];
        }
        __builtin_amdgcn_s_setprio(1);
        #pragma unroll
        for (int m = 0; m < 4; ++m)
            #pragma unroll
            for (int n = 0; n < 4; ++n)
                acc[m][n] = MFMA16(bfr[n], af[m], acc[m][n]);   // C^T tile
        __builtin_amdgcn_s_setprio(0);
        __syncthreads();
    }

    const int which = n0 / CDIM;                // 0=q 1=k 2=v, uniform per block
    #pragma unroll
    for (int m = 0; m < 4; ++m) {
        const int rg = m0 + wr * 64 + m * 16 + lq;
        const int b = rg >> 11, t = rg & (TSEQ - 1);
        #pragma unroll
        for (int n = 0; n < 4; ++n) {
            const int cg = n0 + wc * 64 + n * 16 + (g << 2);
            const int c  = cg - which * CDIM;
            const int h  = c >> 6, d = c & 63;
            const size_t bh = (size_t)(b * HNUM + h);
            const float4 bv = *(const float4*)&bias[cg];
            const float v0 = acc[m][n][0] + bv.x;
            const float v1 = acc[m][n][1] + bv.y;
            const float v2 = acc[m][n][2] + bv.z;
            const float v3 = acc[m][n][3] + bv.w;
            if (which == 0) {
                const float s = 0.1803368801111243f;   // 0.125 * log2(e)
                ushort4 pv;
                pv.x = f2b(v0 * s); pv.y = f2b(v1 * s);
                pv.z = f2b(v2 * s); pv.w = f2b(v3 * s);
                *(ushort4*)&qb[(bh * TSEQ + t) * DHEAD + d] = pv;
            } else if (which == 1) {
                ushort4 pv;
                pv.x = f2b(v0); pv.y = f2b(v1); pv.z = f2b(v2); pv.w = f2b(v3);
                *(ushort4*)&kb[(bh * TSEQ + t) * DHEAD + d] = pv;
            } else {
                vtb[(bh * DHEAD + d + 0) * TSEQ + t] = f2b(v0);
                vtb[(bh * DHEAD + d + 1) * TSEQ + t] = f2b(v1);
                vtb[(bh * DHEAD + d + 2) * TSEQ + t] = f2b(v2);
                vtb[(bh * DHEAD + d + 3) * TSEQ + t] = f2b(v3);
            }
        }
    }
}

// ---------------- GEMM2: out projection, BM=64 x BN=128 -> 768 blocks --------
// 3 blocks/CU exactly (vs 384 blocks = 1.5/CU avg with 2-vs-1 imbalance).
// Wave tile 32x64 (acc 2x4). Same 2-buf cadence + XOR swizzle + C^T epilogue.
template<int NX>
__global__ __launch_bounds__(256) void gemm_out(
        const u16* __restrict__ A, const u16* __restrict__ Bt,
        const float* __restrict__ bias, float* __restrict__ outf, int K) {
    __shared__ u16 sA[2][64 * 32];
    __shared__ u16 sB[2][128 * 32];
    const int tid = threadIdx.x;
    const int lane = tid & 63;
    const int w = tid >> 6;
    const int wr = w >> 1, wc = w & 1;          // 32-row half x 64-col half
    const int g = lane >> 4, lq = lane & 15;
    const int cpx = gridDim.x >> 3;
    const int wg = ((int)blockIdx.x & 7) * cpx + ((int)blockIdx.x >> 3);
    const int bx = wg % NX, by = wg / NX;
    const int m0 = by * 64, n0 = bx * 128;

    f32x4 acc[2][4] = {};

    auto stage = [&](int buf, int kt) {
        {
            int c = tid;                        // A: 256 chunks of 16B
            int r = c >> 2, s = c & 3;
            int l = s ^ ((r >> 1) & 3);
            gload_lds(A + (size_t)(m0 + r) * K + kt * 32 + l * 8, &sA[buf][c * 8]);
        }
        #pragma unroll
        for (int i = 0; i < 2; ++i) {           // B: 512 chunks
            int c = i * 256 + tid;
            int r = c >> 2, s = c & 3;
            int l = s ^ ((r >> 1) & 3);
            gload_lds(Bt + (size_t)(n0 + r) * K + kt * 32 + l * 8, &sB[buf][c * 8]);
        }
    };

    const int KT = K / 32;                      // 24
    stage(0, 0);
    __syncthreads();
    for (int kt = 0; kt < KT; ++kt) {
        if (kt + 1 < KT) stage((kt + 1) & 1, kt + 1);
        const u16* cA = sA[kt & 1];
        const u16* cB = sB[kt & 1];
        bf16x8 af[2], bfr[4];
        #pragma unroll
        for (int m = 0; m < 2; ++m) {
            int r = wr * 32 + m * 16 + lq;
            af[m] = *(const bf16x8*)&cA[r * 32 + ((g ^ ((r >> 1) & 3)) << 3)];
        }
        #pragma unroll
        for (int n = 0; n < 4; ++n) {
            int r = wc * 64 + n * 16 + lq;
            bfr[n] = *(const bf16x8*)&cB[r * 32 + ((g ^ ((r >> 1) & 3)) << 3)];
        }
        __builtin_amdgcn_s_setprio(1);
        #pragma unroll
        for (int m = 0; m < 2; ++m)
            #pragma unroll
            for (int n = 0; n < 4; ++n)
                acc[m][n] = MFMA16(bfr[n], af[m], acc[m][n]);   // C^T tile
        __builtin_amdgcn_s_setprio(0);
        __syncthreads();
    }

    #pragma unroll
    for (int m = 0; m < 2; ++m) {
        const int rg = m0 + wr * 32 + m * 16 + lq;
        #pragma unroll
        for (int n = 0; n < 4; ++n) {
            const int cg = n0 + wc * 64 + n * 16 + (g << 2);
            const float4 bv = *(const float4*)&bias[cg];
            float4 ov;
            ov.x = acc[m][n][0] + bv.x;
            ov.y = acc[m][n][1] + bv.y;
            ov.z = acc[m][n][2] + bv.z;
            ov.w = acc[m][n][3] + bv.w;
            *(float4*)&outf[(size_t)rg * CDIM + cg] = ov;
        }
    }
}

// ---------------- causal flash attention (R11 kernel, reverted) --------------
// 1536 blocks (32 q-tiles x 48 bh), LONGEST FIRST. 256 threads = 4 waves,
// wave owns 16 q rows of a 64-row q-tile. KVBLK=64 double-buffered.
// Swapped QK^T, in-register P, defer-max (THR=8, exp2), MFMA row-sum, setprio.
__global__ __launch_bounds__(256, 4) void attn_fwd(
        const u16* __restrict__ qb, const u16* __restrict__ kb,
        const u16* __restrict__ vtb, u16* __restrict__ yb) {
    __shared__ u16 sK[2][64 * 64];
    __shared__ u16 sVt[2][64 * 64];
    const int qt = 31 - (int)(blockIdx.x / BH);  // 64-row q-tile, longest first
    const int bh = blockIdx.x % BH;
    const int b = bh / HNUM, h = bh % HNUM;
    const int tid = threadIdx.x, lane = tid & 63, w = tid >> 6;   // w 0..3
    const int g = lane >> 4, lq = lane & 15;
    const int qlo = qt * 64 + w * 16;            // wave's 16 q rows
    const u16* qbase = qb  + (size_t)bh * TSEQ * DHEAD;
    const u16* kbase = kb  + (size_t)bh * TSEQ * DHEAD;
    const u16* vbase = vtb + (size_t)bh * DHEAD * TSEQ;

    bf16x8 qf[2];
    #pragma unroll
    for (int ks = 0; ks < 2; ++ks)
        qf[ks] = *(const bf16x8*)&qbase[(size_t)(qlo + lq) * DHEAD + ks * 32 + g * 8];

    union { unsigned u[4]; bf16x8 v; } ones;
    #pragma unroll
    for (int i = 0; i < 4; ++i) ones.u[i] = 0x3f803f80u;

    f32x4 o[4] = {};
    f32x4 ls = {};                               // row sums, O-layout (q=g*4+j)
    float mx = -__builtin_inff();

    auto STAGE = [&](int buf, int kt) {
        const int k0 = kt << 6;
        #pragma unroll
        for (int i = 0; i < 2; ++i) {
            int chunk = i * 256 + tid;           // 512 chunks of 16B per tile
            int srow = chunk >> 3;
            int cb = ((chunk & 7) << 4) ^ ((srow & 7) << 4);   // logical byte col
            gload_lds(kbase + (size_t)(k0 + srow) * DHEAD + (cb >> 1), &sK[buf][chunk * 8]);
            gload_lds(vbase + (size_t)srow * TSEQ + k0 + (cb >> 1),    &sVt[buf][chunk * 8]);
        }
    };

    const int nk = qt + 1;
    STAGE(0, 0);
    __syncthreads();
    for (int kt = 0; kt < nk; ++kt) {
        const int k0 = kt << 6;
        if (kt + 1 < nk) STAGE((kt + 1) & 1, kt + 1);   // prefetch overlaps compute
        const u16* cK = sK[kt & 1];
        const u16* cV = sVt[kt & 1];
        f32x4 s[4];
        #pragma unroll
        for (int n = 0; n < 4; ++n) s[n] = f32x4{0.f, 0.f, 0.f, 0.f};
        __builtin_amdgcn_s_setprio(1);
        #pragma unroll
        for (int n = 0; n < 4; ++n) {
            #pragma unroll
            for (int ks = 0; ks < 2; ++ks) {
                int r = n * 16 + lq;
                int lb = (r * 128 + (ks * 32 + g * 8) * 2) ^ ((r & 7) << 4);
                bf16x8 kf = *(const bf16x8*)((const char*)cK + lb);
                s[n] = MFMA16(kf, qf[ks], s[n]);
            }
        }
        __builtin_amdgcn_s_setprio(0);
        if (k0 + 63 > qlo) {
            const int qa = qlo + lq;
            #pragma unroll
            for (int n = 0; n < 4; ++n)
                #pragma unroll
                for (int j = 0; j < 4; ++j)
                    if (k0 + n * 16 + g * 4 + j > qa) s[n][j] = -__builtin_inff();
        }
        float t0 = fmaxf(fmaxf(s[0][0], s[0][1]), fmaxf(s[0][2], s[0][3]));
        float t1 = fmaxf(fmaxf(s[1][0], s[1][1]), fmaxf(s[1][2], s[1][3]));
        float t2 = fmaxf(fmaxf(s[2][0], s[2][1]), fmaxf(s[2][2], s[2][3]));
        float t3 = fmaxf(fmaxf(s[3][0], s[3][1]), fmaxf(s[3][2], s[3][3]));
        float tmax = fmaxf(fmaxf(t0, t1), fmaxf(t2, t3));
        tmax = fmaxf(tmax, __shfl_xor(tmax, 16));
        tmax = fmaxf(tmax, __shfl_xor(tmax, 32));
        if (__any(tmax > mx + 8.0f)) {
            float mnew = fmaxf(mx, tmax);
            float sc = fexp2(mx - mnew);
            mx = mnew;
            #pragma unroll
            for (int j = 0; j < 4; ++j) {
                float scj = __shfl(sc, (lane & 48) | ((g << 2) + j));
                ls[j] *= scj;
                #pragma unroll
                for (int n = 0; n < 4; ++n) o[n][j] *= scj;
            }
        }
        #pragma unroll
        for (int n = 0; n < 4; ++n)
            #pragma unroll
            for (int j = 0; j < 4; ++j)
                s[n][j] = fexp2(s[n][j] - mx);
        unsigned apk[4], bpk[4];
        #pragma unroll
        for (int n = 0; n < 4; ++n) {
            apk[n] = cvtpk(s[n][0], s[n][1]);
            bpk[n] = cvtpk(s[n][2], s[n][3]);
        }
        const int s0l = lq + ((lane & 16) << 1);
        const bool hi = (lane & 32) != 0;
        #pragma unroll
        for (int ks = 0; ks < 2; ++ks) {
            unsigned A0  = (unsigned)__shfl((int)apk[2 * ks],     s0l);
            unsigned B0  = (unsigned)__shfl((int)bpk[2 * ks],     s0l);
            unsigned A1  = (unsigned)__shfl((int)apk[2 * ks + 1], s0l);
            unsigned B1  = (unsigned)__shfl((int)bpk[2 * ks + 1], s0l);
            unsigned A0h = (unsigned)__shfl((int)apk[2 * ks],     s0l + 16);
            unsigned B0h = (unsigned)__shfl((int)bpk[2 * ks],     s0l + 16);
            unsigned A1h = (unsigned)__shfl((int)apk[2 * ks + 1], s0l + 16);
            unsigned B1h = (unsigned)__shfl((int)bpk[2 * ks + 1], s0l + 16);
            union { unsigned u[4]; bf16x8 v; } pa;
            pa.u[0] = hi ? A1  : A0;
            pa.u[1] = hi ? B1  : B0;
            pa.u[2] = hi ? A1h : A0h;
            pa.u[3] = hi ? B1h : B0h;
            __builtin_amdgcn_s_setprio(1);
            #pragma unroll
            for (int n = 0; n < 4; ++n) {
                int d = n * 16 + lq;
                int lb = (d * 128 + (ks * 32 + g * 8) * 2) ^ ((d & 7) << 4);
                bf16x8 vf = *(const bf16x8*)((const char*)cV + lb);
                o[n] = MFMA16(pa.v, vf, o[n]);
            }
            ls = MFMA16(pa.v, ones.v, ls);
            __builtin_amdgcn_s_setprio(0);
        }
        __syncthreads();
    }

    #pragma unroll
    for (int j = 0; j < 4; ++j) {
        float inv = 1.f / ls[j];
        const int t = qlo + g * 4 + j;
        #pragma unroll
        for (int n = 0; n < 4; ++n) {
            const int c = h * DHEAD + n * 16 + lq;
            yb[((size_t)b * TSEQ + t) * CDIM + c] = f2b(o[n][j] * inv);
        }
    }
}

extern "C" void kernel_launch(void* const* d_in, const int* in_sizes, int n_in,
                              void* d_out, int out_size, void* d_ws, size_t ws_size,
                              hipStream_t stream) {
    const float* x      = (const float*)d_in[0];
    const float* W_attn = (const float*)d_in[1];
    const float* b_attn = (const float*)d_in[2];
    const float* W_proj = (const float*)d_in[3];
    const float* b_proj = (const float*)d_in[4];
    float* out = (float*)d_out;

    // workspace layout (bf16 = u16). yb aliases xb (xb dead after GEMM1).
    u16* ws = (u16*)d_ws;
    u16* xb     = ws;                                   // [BTOT][CDIM]
    u16* yb     = xb;                                   // [BTOT][CDIM] (alias)
    u16* WattnT = xb     + (size_t)BTOT * CDIM;         // [NQKV][CDIM]
    u16* WprojT = WattnT + (size_t)NQKV * CDIM;         // [CDIM][CDIM]
    u16* qb     = WprojT + (size_t)CDIM * CDIM;         // [BH][TSEQ][DHEAD]
    u16* kb     = qb     + (size_t)BH * TSEQ * DHEAD;
    u16* vtb    = kb     + (size_t)BH * TSEQ * DHEAD;   // [BH][DHEAD][TSEQ]

    // 1) fused prep: x cast + both weight transposes (one launch)
    prep<<<dim3(CAST_BLKS + TA_BLKS + TP_BLKS), 256, 0, stream>>>(
        x, xb, W_attn, W_proj, WattnT, WprojT);

    // 2) QKV projection + scatter (1152 blocks, XCD-swizzled, conflict-free LDS)
    gemm_qkv<NQKV / 128><<<dim3((NQKV / 128) * (BTOT / 128)), 256, 0, stream>>>(
        xb, WattnT, b_attn, qb, kb, vtb, CDIM);

    // 3) causal flash attention (1536 blocks, 16 q-rows/wave, longest first)
    attn_fwd<<<dim3((TSEQ / 64) * BH), 256, 0, stream>>>(qb, kb, vtb, yb);

    // 4) output projection (768 blocks of 64x128 = 3/CU exact, XCD-swizzled)
    gemm_out<CDIM / 128><<<dim3((CDIM / 128) * (BTOT / 64)), 256, 0, stream>>>(
        yb, WprojT, b_proj, out, CDIM);
}